// Round 11
// baseline (182.682 us; speedup 1.0000x reference)
//
#include <hip/hip_runtime.h>
#include <math.h>

#define L_SEQ 1024
#define M_ROWS 2048
#define PI_F 3.14159265358979323846f

typedef short bf16x8 __attribute__((ext_vector_type(8)));
typedef float f32x4 __attribute__((ext_vector_type(4)));

__device__ __forceinline__ unsigned short bf16_rne(float x) {
    union { float f; unsigned u; } v; v.f = x;
    unsigned r = v.u + 0x7fffu + ((v.u >> 16) & 1u);
    return (unsigned short)(r >> 16);
}
__device__ __forceinline__ float bf16_tof(unsigned short h) {
    union { unsigned u; float f; } v; v.u = ((unsigned)h) << 16;
    return v.f;
}
__device__ __forceinline__ void split2(float x, unsigned short &h, unsigned short &l) {
    h = bf16_rne(x);
    l = bf16_rne(x - bf16_tof(h));
}
__device__ __forceinline__ float gelu_exact(float x) {
    return 0.5f * x * (1.0f + erff(x * 0.70710678118654752f));
}
__device__ __forceinline__ f32x4 mfma16(bf16x8 a, bf16x8 b, f32x4 c) {
    return __builtin_amdgcn_mfma_f32_16x16x32_bf16(a, b, c, 0, 0, 0);
}
__device__ __forceinline__ void gload_lds16(const unsigned short* g, unsigned short* l) {
    __builtin_amdgcn_global_load_lds(
        (const __attribute__((address_space(1))) void*)g,
        (__attribute__((address_space(3))) void*)l, 16, 0, 0);
}

// Stage R x 32 bf16 tile into LDS (row = 64B), pre-swizzled source.
// Participating threads: R*4 (full waves).
__device__ __forceinline__ void stage_tile(
    const unsigned short* __restrict__ src, int ld, int rowBase, int k0,
    unsigned short* lds_tile, int R)
{
    const int tid = threadIdx.x;
    if (tid < R * 4) {
        const int r = tid >> 2;
        const int c = (tid & 3) ^ ((r >> 1) & 3);
        const unsigned short* g = src + (size_t)(rowBase + r) * ld + k0 + c * 8;
        unsigned short* l = lds_tile + (tid >> 6) * 512;   // wave-uniform base
        gload_lds16(g, l);
    }
}

// LDS-staged split-bf16 GEMM core. 512 threads = 8 waves (2m x 4n).
// Block tile = (32*MI) x (64*NI). K-step 32, double-buffered.
template<int MI, int NI>
__device__ __forceinline__ void lds_gemm(
    unsigned short* lds,
    const unsigned short* Ah_, const unsigned short* Al_, int lda, int aRow,
    const unsigned short* Bh_, const unsigned short* Bl_, int ldb, int bRow,
    int k0, int nk, f32x4 (&acc)[MI][NI])
{
    constexpr int RA = MI * 32, RB = NI * 64;
    constexpr int SZA = RA * 32;
    constexpr int SZB = RB * 32;
    constexpr int BUF = 2 * SZA + 2 * SZB;
    const int tid = threadIdx.x, lane = tid & 63;
    const int wm = (tid >> 8) & 1;
    const int wn = (tid >> 6) & 3;

    stage_tile(Ah_, lda, aRow, k0, lds,                 RA);
    stage_tile(Al_, lda, aRow, k0, lds + SZA,           RA);
    stage_tile(Bh_, ldb, bRow, k0, lds + 2 * SZA,       RB);
    stage_tile(Bl_, ldb, bRow, k0, lds + 2 * SZA + SZB, RB);

    for (int ks = 0; ks < nk; ++ks) {
        const int cur = (ks & 1) * BUF;
        const int nxt = ((ks & 1) ^ 1) * BUF;
        __syncthreads();
        if (ks + 1 < nk) {
            const int kk = k0 + (ks + 1) * 32;
            stage_tile(Ah_, lda, aRow, kk, lds + nxt,                 RA);
            stage_tile(Al_, lda, aRow, kk, lds + nxt + SZA,           RA);
            stage_tile(Bh_, ldb, bRow, kk, lds + nxt + 2 * SZA,       RB);
            stage_tile(Bl_, ldb, bRow, kk, lds + nxt + 2 * SZA + SZB, RB);
        }
        const int lr = lane & 15, j = lane >> 4;
        bf16x8 ah[MI], al[MI], bh[NI], bl[NI];
#pragma unroll
        for (int mi = 0; mi < MI; ++mi) {
            const int r = wm * (MI * 16) + mi * 16 + lr;
            const int off = cur + r * 32 + ((j ^ ((r >> 1) & 3)) << 3);
            ah[mi] = *(const bf16x8*)(lds + off);
            al[mi] = *(const bf16x8*)(lds + off + SZA);
        }
#pragma unroll
        for (int ni = 0; ni < NI; ++ni) {
            const int r = wn * (NI * 16) + ni * 16 + lr;
            const int off = cur + 2 * SZA + r * 32 + ((j ^ ((r >> 1) & 3)) << 3);
            bh[ni] = *(const bf16x8*)(lds + off);
            bl[ni] = *(const bf16x8*)(lds + off + SZB);
        }
#pragma unroll
        for (int mi = 0; mi < MI; ++mi)
#pragma unroll
            for (int ni = 0; ni < NI; ++ni) {
                acc[mi][ni] = mfma16(ah[mi], bh[ni], acc[mi][ni]);
                acc[mi][ni] = mfma16(ah[mi], bl[ni], acc[mi][ni]);
                acc[mi][ni] = mfma16(al[mi], bh[ni], acc[mi][ni]);
            }
    }
}

// ---------------------------------------------------------------------------
// prep: W transpose+split (units 0..271) and X split (units 272..527).
// ---------------------------------------------------------------------------
__global__ __launch_bounds__(512) void prep(
    const float* __restrict__ x,
    const float* __restrict__ Wk1, const float* __restrict__ Wq1,
    const float* __restrict__ Wv,  const float* __restrict__ Wo,
    const float* __restrict__ Wk2, const float* __restrict__ Wq2,
    unsigned short* __restrict__ Wt_h, unsigned short* __restrict__ Wt_l,
    unsigned short* __restrict__ XYh,  unsigned short* __restrict__ XYl)
{
    const int u = blockIdx.x;
    const int tid = threadIdx.x;
    if (u < 272) {
        __shared__ float T[64 * 65];
        const int kT = u & 7, ty = u >> 3;
        const float* src; int srcN, dstRowBase, nBase;
        if (ty < 8)       { src = Wk1; srcN = 512; dstRowBase = 0;    nBase = ty * 64; }
        else if (ty < 16) { src = Wq1; srcN = 512; dstRowBase = 512;  nBase = (ty-8)*64; }
        else if (ty < 24) { src = Wv;  srcN = 512; dstRowBase = 1024; nBase = (ty-16)*64; }
        else if (ty < 32) { src = Wo;  srcN = 512; dstRowBase = 1536; nBase = (ty-24)*64; }
        else if (ty == 32){ src = Wk2; srcN = 64;  dstRowBase = 2048; nBase = 0; }
        else              { src = Wq2; srcN = 64;  dstRowBase = 2112; nBase = 0; }
        const int k0 = kT * 64;
        {
            const int r = tid >> 3, c0 = (tid & 7) * 8;
#pragma unroll
            for (int i = 0; i < 2; ++i) {
                float4 v = *reinterpret_cast<const float4*>(
                    src + (size_t)(k0 + r) * srcN + nBase + c0 + i*4);
                T[r*65 + c0+i*4+0] = v.x; T[r*65 + c0+i*4+1] = v.y;
                T[r*65 + c0+i*4+2] = v.z; T[r*65 + c0+i*4+3] = v.w;
            }
        }
        __syncthreads();
        {
            const int n = tid >> 3, kk0 = (tid & 7) * 8;
            const size_t base = (size_t)(dstRowBase + nBase + n) * 512 + k0 + kk0;
#pragma unroll
            for (int i = 0; i < 8; ++i) {
                unsigned short h, l;
                split2(T[(kk0 + i)*65 + n], h, l);
                Wt_h[base + i] = h; Wt_l[base + i] = l;
            }
        }
    } else {
        const int xb = u - 272;   // 0..255
#pragma unroll
        for (int ii = 0; ii < 2; ++ii) {
            const size_t i = (size_t)xb * 1024 + ii * 512 + tid;
            float4 v = reinterpret_cast<const float4*>(x)[i];
            unsigned short h0,h1,h2,h3,l0,l1,l2,l3;
            split2(v.x,h0,l0); split2(v.y,h1,l1); split2(v.z,h2,l2); split2(v.w,h3,l3);
            unsigned long long hp = (unsigned long long)h0 | ((unsigned long long)h1<<16)
                                  | ((unsigned long long)h2<<32) | ((unsigned long long)h3<<48);
            unsigned long long lp = (unsigned long long)l0 | ((unsigned long long)l1<<16)
                                  | ((unsigned long long)l2<<32) | ((unsigned long long)l3<<48);
            reinterpret_cast<unsigned long long*>(XYh)[i] = hp;
            reinterpret_cast<unsigned long long*>(XYl)[i] = lp;
        }
    }
}

// ---------------------------------------------------------------------------
// qkv: 192 units of 128x128; gelu on k/q segs, V transposed per batch.
// ---------------------------------------------------------------------------
__global__ __launch_bounds__(512) void qkv_mfma(
    const unsigned short* __restrict__ XYh, const unsigned short* __restrict__ XYl,
    const unsigned short* __restrict__ Wt_h, const unsigned short* __restrict__ Wt_l,
    const float* __restrict__ bk1, const float* __restrict__ bq1, const float* __restrict__ bv,
    unsigned short* __restrict__ Hk_h, unsigned short* __restrict__ Hk_l,
    unsigned short* __restrict__ Hq_h, unsigned short* __restrict__ Hq_l,
    unsigned short* __restrict__ Vt_h, unsigned short* __restrict__ Vt_l)
{
    __shared__ __align__(16) unsigned short lds[32768];   // 64KB for <4,2>
    const int tid = threadIdx.x, lane = tid & 63;
    const int nT = blockIdx.x % 12, mT = blockIdx.x / 12;
    const int mBase = mT * 128, nBase = nT * 128;
    const int wm = (tid >> 8) & 1, wn = (tid >> 6) & 3;
    f32x4 acc[4][2];
#pragma unroll
    for (int i = 0; i < 4; ++i)
#pragma unroll
        for (int jj = 0; jj < 2; ++jj) acc[i][jj] = (f32x4){0.f,0.f,0.f,0.f};
    lds_gemm<4,2>(lds, XYh, XYl, 512, mBase, Wt_h, Wt_l, 512, nBase, 0, 16, acc);
    const int seg = nBase >> 9;
    const float* bias = (seg == 0) ? bk1 : (seg == 1) ? bq1 : bv;
#pragma unroll
    for (int mi = 0; mi < 4; ++mi)
#pragma unroll
    for (int ni = 0; ni < 2; ++ni)
#pragma unroll
    for (int r = 0; r < 4; ++r) {
        const int row = mBase + wm*64 + mi*16 + (lane>>4)*4 + r;
        const int col = nBase + wn*32 + ni*16 + (lane&15);
        const int nW = col & 511;
        float v = acc[mi][ni][r] + bias[nW];
        if (seg < 2) v = gelu_exact(v);
        unsigned short h, l;
        split2(v, h, l);
        if (seg == 0)      { Hk_h[(size_t)row*512 + nW] = h; Hk_l[(size_t)row*512 + nW] = l; }
        else if (seg == 1) { Hq_h[(size_t)row*512 + nW] = h; Hq_l[(size_t)row*512 + nW] = l; }
        else {
            const size_t o = (size_t)((row >> 10)*512 + nW) * 1024 + (row & 1023);
            Vt_h[o] = h; Vt_l[o] = l;
        }
    }
}

// ---------------------------------------------------------------------------
// phase heads: 64 units of 64 rows; p = tanh(H@W2+b2)*pi -> [cos|sin] hi/lo.
// ---------------------------------------------------------------------------
__global__ __launch_bounds__(512) void phase_mfma(
    const unsigned short* __restrict__ Hk_h, const unsigned short* __restrict__ Hk_l,
    const unsigned short* __restrict__ Hq_h, const unsigned short* __restrict__ Hq_l,
    const unsigned short* __restrict__ Wt_h, const unsigned short* __restrict__ Wt_l,
    const float* __restrict__ bk2, const float* __restrict__ bq2,
    unsigned short* __restrict__ CSk_h, unsigned short* __restrict__ CSk_l,
    unsigned short* __restrict__ CSq_h, unsigned short* __restrict__ CSq_l)
{
    __shared__ __align__(16) unsigned short lds[16384];   // 32KB for <2,1>
    const int tid = threadIdx.x, lane = tid & 63;
    const int enc = blockIdx.x & 1, mT = blockIdx.x >> 1;
    const unsigned short* Ah_ = enc ? Hq_h : Hk_h;
    const unsigned short* Al_ = enc ? Hq_l : Hk_l;
    const float* b2 = enc ? bq2 : bk2;
    unsigned short* Ch = enc ? CSq_h : CSk_h;
    unsigned short* Cl = enc ? CSq_l : CSk_l;
    const int wm = (tid >> 8) & 1, wn = (tid >> 6) & 3;
    f32x4 acc[2][1];
#pragma unroll
    for (int i = 0; i < 2; ++i) acc[i][0] = (f32x4){0.f,0.f,0.f,0.f};
    lds_gemm<2,1>(lds, Ah_, Al_, 512, mT*64, Wt_h, Wt_l, 512, 2048 + enc*64, 0, 16, acc);
#pragma unroll
    for (int mi = 0; mi < 2; ++mi)
#pragma unroll
    for (int r = 0; r < 4; ++r) {
        const int row = mT*64 + wm*32 + mi*16 + (lane>>4)*4 + r;
        const int j = wn*16 + (lane&15);
        float p = acc[mi][0][r] + b2[j];
        p = tanhf(p) * PI_F;
        float s, c;
        sincosf(p, &s, &c);
        unsigned short h, l;
        split2(c, h, l);
        Ch[(size_t)row*128 + j] = h; Cl[(size_t)row*128 + j] = l;
        split2(s, h, l);
        Ch[(size_t)row*128 + 64 + j] = h; Cl[(size_t)row*128 + 64 + j] = l;
    }
}

// ---------------------------------------------------------------------------
// fattn: fused scores + causal AV. Block = (b, tT of 32 t-rows, dT of 64 d).
// Q tile persistent in LDS; per s-chunk(64): QK^T -> mask -> S(bf16 hi/lo) in
// swizzled LDS -> S@V accumulate. Writes R fp32 once. Grid: longest-t first.
// LDS map (ushort idx): Qh p*1024 (p0..3), Ql 4096+p*1024,
//   Sh 8192+p*1024 (p0..1), Sl 10240+p*1024, stage bufs 12288 / 16384
//   (each: hi +0, lo +2048). Total 20480 (40KB) -> 2+ blocks/CU.
// ---------------------------------------------------------------------------
__global__ __launch_bounds__(512) void fattn(
    const unsigned short* __restrict__ CSq_h, const unsigned short* __restrict__ CSq_l,
    const unsigned short* __restrict__ CSk_h, const unsigned short* __restrict__ CSk_l,
    const unsigned short* __restrict__ Vt_h, const unsigned short* __restrict__ Vt_l,
    float* __restrict__ R)
{
    __shared__ __align__(16) unsigned short lds[20480];
    const int b  = blockIdx.z;
    const int tT = (int)gridDim.y - 1 - blockIdx.y;   // descending t: long blocks first
    const int dT = blockIdx.x;
    const int t0 = tT * 32;
    const int tid = threadIdx.x, lane = tid & 63;
    const int wm = (tid >> 8) & 1, wn = (tid >> 6) & 3;
    const int lr = lane & 15, j = lane >> 4;

    // stage Q panels once (drained by first barrier in chunk loop)
#pragma unroll
    for (int p = 0; p < 4; ++p) {
        stage_tile(CSq_h, 128, b*1024 + t0, p*32, lds + p*1024, 32);
        stage_tile(CSq_l, 128, b*1024 + t0, p*32, lds + 4096 + p*1024, 32);
    }

    const int nch = (t0 >> 6) + 1;
    f32x4 accv = (f32x4){0.f, 0.f, 0.f, 0.f};

    for (int c = 0; c < nch; ++c) {
        const int s0 = c * 64;
        // ---- scores: S[32t x 64s] = Q . CSk^T over k=128 (4 steps) ----
        f32x4 accs = (f32x4){0.f, 0.f, 0.f, 0.f};
        __syncthreads();   // stage bufs free (prev chunk AV done); Q drained
        stage_tile(CSk_h, 128, b*1024 + s0, 0, lds + 12288, 64);
        stage_tile(CSk_l, 128, b*1024 + s0, 0, lds + 12288 + 2048, 64);
#pragma unroll
        for (int ks = 0; ks < 4; ++ks) {
            const int cur = 12288 + (ks & 1) * 4096;
            const int nxt = 12288 + ((ks & 1) ^ 1) * 4096;
            __syncthreads();
            if (ks + 1 < 4) {
                stage_tile(CSk_h, 128, b*1024 + s0, (ks+1)*32, lds + nxt, 64);
                stage_tile(CSk_l, 128, b*1024 + s0, (ks+1)*32, lds + nxt + 2048, 64);
            }
            const int ra = wm*16 + lr;
            const int offa = ks*1024 + ra*32 + ((j ^ ((ra>>1)&3)) << 3);
            bf16x8 ah = *(const bf16x8*)(lds + offa);
            bf16x8 al = *(const bf16x8*)(lds + offa + 4096);
            const int rb = wn*16 + lr;
            const int offb = cur + rb*32 + ((j ^ ((rb>>1)&3)) << 3);
            bf16x8 bh = *(const bf16x8*)(lds + offb);
            bf16x8 bl = *(const bf16x8*)(lds + offb + 2048);
            accs = mfma16(ah, bh, accs);
            accs = mfma16(ah, bl, accs);
            accs = mfma16(al, bh, accs);
        }
        // ---- convert + causal mask -> S tile (staged swizzle format) ----
        {
            const int sl = wn*16 + (lane & 15);          // 0..63
            const int panel = sl >> 5, k = sl & 31;
            const int slot = k >> 3, within = k & 7;
#pragma unroll
            for (int rr = 0; rr < 4; ++rr) {
                const int row = wm*16 + (lane>>4)*4 + rr;   // 0..31
                const float v = (s0 + sl <= t0 + row) ? accs[rr] : 0.f;
                unsigned short h, l;
                split2(v, h, l);
                const int addr = 8192 + panel*1024 + row*32
                               + ((slot ^ ((row>>1)&3)) << 3) + within;
                lds[addr] = h;
                lds[addr + 2048] = l;
            }
        }
        __syncthreads();   // S visible; stage bufs reusable
        // ---- AV: accv += S . Vt^T over s (2 steps of 32) ----
        stage_tile(Vt_h, 1024, b*512 + dT*64, s0, lds + 12288, 64);
        stage_tile(Vt_l, 1024, b*512 + dT*64, s0, lds + 12288 + 2048, 64);
#pragma unroll
        for (int ks = 0; ks < 2; ++ks) {
            const int cur = 12288 + (ks & 1) * 4096;
            const int nxt = 12288 + ((ks & 1) ^ 1) * 4096;
            __syncthreads();
            if (ks + 1 < 2) {
                stage_tile(Vt_h, 1024, b*512 + dT*64, s0 + 32, lds + nxt, 64);
                stage_tile(Vt_l, 1024, b*512 + dT*64, s0 + 32, lds + nxt + 2048, 64);
            }
            const int ra = wm*16 + lr;
            const int offa = 8192 + ks*1024 + ra*32 + ((j ^ ((ra>>1)&3)) << 3);
            bf16x8 ah = *(const bf16x8*)(lds + offa);
            bf16x8 al = *(const bf16x8*)(lds + offa + 2048);
            const int rb = wn*16 + lr;
            const int offb = cur + rb*32 + ((j ^ ((rb>>1)&3)) << 3);
            bf16x8 bh = *(const bf16x8*)(lds + offb);
            bf16x8 bl = *(const bf16x8*)(lds + offb + 2048);
            accv = mfma16(ah, bh, accv);
            accv = mfma16(ah, bl, accv);
            accv = mfma16(al, bh, accv);
        }
    }
    // ---- write R fp32 ----
#pragma unroll
    for (int rr = 0; rr < 4; ++rr) {
        const int row = b*1024 + t0 + wm*16 + (lane>>4)*4 + rr;
        const int d = dT*64 + wn*16 + (lane&15);
        R[(size_t)row*512 + d] = accv[rr];
    }
}

// ---------------------------------------------------------------------------
// ln: one row per block; LN(R/sqrt((t+1)K))*g + b -> Y hi/lo bf16.
// ---------------------------------------------------------------------------
__global__ __launch_bounds__(512) void ln_kernel(
    const float* __restrict__ R, const float* __restrict__ g,
    const float* __restrict__ bb,
    unsigned short* __restrict__ Yh, unsigned short* __restrict__ Yl)
{
    __shared__ float fbuf[16];
    const int row = blockIdx.x;
    const int t = row & (L_SEQ - 1);
    const int tid = threadIdx.x;
    const int lane = tid & 63, wid = tid >> 6;
    const float scale = rsqrtf((float)(t + 1) * 64.0f);
    float v = R[(size_t)row * 512 + tid] * scale;
    float s = v, q = v * v;
#pragma unroll
    for (int off = 32; off >= 1; off >>= 1) {
        s += __shfl_down(s, off);
        q += __shfl_down(q, off);
    }
    if (lane == 0) { fbuf[wid] = s; fbuf[8 + wid] = q; }
    __syncthreads();
    float S = 0.f, Q = 0.f;
#pragma unroll
    for (int w = 0; w < 8; ++w) { S += fbuf[w]; Q += fbuf[8 + w]; }
    const float mu  = S * (1.f / 512.f);
    const float var = Q * (1.f / 512.f) - mu * mu;
    const float rr = rsqrtf(var + 1e-5f);
    const float y = (v - mu) * rr * g[tid] + bb[tid];
    unsigned short h, l;
    split2(y, h, l);
    Yh[(size_t)row*512 + tid] = h;
    Yl[(size_t)row*512 + tid] = l;
}

// ---------------------------------------------------------------------------
// out: 128 units of 128x64; out = x + Y @ Wo + bo.
// ---------------------------------------------------------------------------
__global__ __launch_bounds__(512) void out_mfma(
    const unsigned short* __restrict__ Yh, const unsigned short* __restrict__ Yl,
    const unsigned short* __restrict__ Wt_h, const unsigned short* __restrict__ Wt_l,
    const float* __restrict__ bo, const float* __restrict__ x,
    float* __restrict__ out)
{
    __shared__ __align__(16) unsigned short lds[24576];   // 48KB for <4,1>
    const int tid = threadIdx.x, lane = tid & 63;
    const int mT = blockIdx.x >> 3, nT = blockIdx.x & 7;
    const int mBase = mT * 128;
    const int wm = (tid >> 8) & 1, wn = (tid >> 6) & 3;
    f32x4 acc[4][1];
#pragma unroll
    for (int i = 0; i < 4; ++i) acc[i][0] = (f32x4){0.f,0.f,0.f,0.f};
    lds_gemm<4,1>(lds, Yh, Yl, 512, mBase, Wt_h, Wt_l, 512, 1536 + nT*64, 0, 16, acc);
#pragma unroll
    for (int mi = 0; mi < 4; ++mi)
#pragma unroll
    for (int r = 0; r < 4; ++r) {
        const int row = mBase + wm*64 + mi*16 + (lane>>4)*4 + r;
        const int col = nT*64 + wn*16 + (lane&15);
        out[(size_t)row*512 + col] =
            acc[mi][0][r] + bo[col] + x[(size_t)row*512 + col];
    }
}

// ---------------------------------------------------------------------------
extern "C" void kernel_launch(void* const* d_in, const int* in_sizes, int n_in,
                              void* d_out, int out_size, void* d_ws, size_t ws_size,
                              hipStream_t stream)
{
    const float* x   = (const float*)d_in[0];
    const float* Wk1 = (const float*)d_in[1];
    const float* bk1 = (const float*)d_in[2];
    const float* Wk2 = (const float*)d_in[3];
    const float* bk2 = (const float*)d_in[4];
    const float* Wq1 = (const float*)d_in[5];
    const float* bq1 = (const float*)d_in[6];
    const float* Wq2 = (const float*)d_in[7];
    const float* bq2 = (const float*)d_in[8];
    const float* Wv  = (const float*)d_in[9];
    const float* bv  = (const float*)d_in[10];
    const float* lng = (const float*)d_in[11];
    const float* lnb = (const float*)d_in[12];
    const float* Wo  = (const float*)d_in[13];
    const float* bo  = (const float*)d_in[14];
    float* out = (float*)d_out;

    unsigned short* us = (unsigned short*)d_ws;
    size_t o = 0;
    unsigned short* Wt_h  = us + o; o += (size_t)2176*512;
    unsigned short* Wt_l  = us + o; o += (size_t)2176*512;
    unsigned short* XYh   = us + o; o += (size_t)2048*512;
    unsigned short* XYl   = us + o; o += (size_t)2048*512;
    unsigned short* Hk_h  = us + o; o += (size_t)2048*512;
    unsigned short* Hk_l  = us + o; o += (size_t)2048*512;
    unsigned short* Hq_h  = us + o; o += (size_t)2048*512;
    unsigned short* Hq_l  = us + o; o += (size_t)2048*512;
    unsigned short* Vt_h  = us + o; o += (size_t)2*512*1024;
    unsigned short* Vt_l  = us + o; o += (size_t)2*512*1024;
    unsigned short* CSk_h = us + o; o += (size_t)2048*128;
    unsigned short* CSk_l = us + o; o += (size_t)2048*128;
    unsigned short* CSq_h = us + o; o += (size_t)2048*128;
    unsigned short* CSq_l = us + o; o += (size_t)2048*128;
    float* R = (float*)(us + o);    o += (size_t)2048*512*2;   // fp32 4MB

    prep<<<528, 512, 0, stream>>>(x, Wk1, Wq1, Wv, Wo, Wk2, Wq2,
                                  Wt_h, Wt_l, XYh, XYl);
    qkv_mfma<<<192, 512, 0, stream>>>(XYh, XYl, Wt_h, Wt_l, bk1, bq1, bv,
                                      Hk_h, Hk_l, Hq_h, Hq_l, Vt_h, Vt_l);
    phase_mfma<<<64, 512, 0, stream>>>(Hk_h, Hk_l, Hq_h, Hq_l, Wt_h, Wt_l,
                                       bk2, bq2, CSk_h, CSk_l, CSq_h, CSq_l);
    fattn<<<dim3(8, 32, 2), 512, 0, stream>>>(CSq_h, CSq_l, CSk_h, CSk_l,
                                              Vt_h, Vt_l, R);
    ln_kernel<<<2048, 512, 0, stream>>>(R, lng, lnb, XYh, XYl);
    out_mfma<<<128, 512, 0, stream>>>(XYh, XYl, Wt_h, Wt_l, bo, x, out);
}